// Round 1
// baseline (199.907 us; speedup 1.0000x reference)
//
#include <hip/hip_runtime.h>
#include <hip/hip_bf16.h>

// Lovasz-Softmax loss, sort-free histogram formulation.
//
// Math: per class, sorting errors descending and accumulating grad*e is
// invariant to permutation within equal-error runs (jaccard value depends only
// on cumulative (i,k)). Quantizing e in [0,1] into NB linear bins gives exact
// cumulative counts at bin boundaries; using the bin center as representative
// bounds the total error by 1/(2*NB) * (j_N - j_0) <= 1/(2*NB) since the
// jaccard sequence is monotone increasing with j_N = 1. NB=512 -> err <= 1e-3,
// far under the 1.9e-2 harness threshold.

#define NCLS 19
#define NB 512
#define HWSZ 262144          // 512*512
#define NPIX 2097152         // 8*512*512
#define HISTW (NCLS * NB)    // 9728 words per histogram copy

__global__ __launch_bounds__(256) void lovasz_hist_kernel(
    const float* __restrict__ pred, const int* __restrict__ tgt,
    unsigned int* __restrict__ gh)
{
    __shared__ unsigned int lh[HISTW];   // packed: low16 = count, high16 = target count
    for (int j = threadIdx.x; j < HISTW; j += 256) lh[j] = 0u;
    __syncthreads();

    const int stride = gridDim.x * 256;
    for (int idx = blockIdx.x * 256 + threadIdx.x; idx < NPIX; idx += stride) {
        const int b  = idx >> 18;          // / (512*512)
        const int hw = idx & (HWSZ - 1);
        const float* base = pred + ((size_t)b * NCLS) * HWSZ + hw;

        float x[NCLS];
        #pragma unroll
        for (int c = 0; c < NCLS; ++c) x[c] = base[(size_t)c * HWSZ];

        float mx = x[0];
        #pragma unroll
        for (int c = 1; c < NCLS; ++c) mx = fmaxf(mx, x[c]);

        float s = 0.f;
        #pragma unroll
        for (int c = 0; c < NCLS; ++c) { x[c] = __expf(x[c] - mx); s += x[c]; }
        const float inv = 1.f / s;

        const int t = tgt[idx];
        #pragma unroll
        for (int c = 0; c < NCLS; ++c) {
            const float p = x[c] * inv;
            const bool ist = (c == t);
            float e = ist ? (1.f - p) : p;      // error in [0,1] (tiny fp slop ok)
            int q = (int)(e * (float)NB);       // trunc; e<0 slop -> 0
            q = q < 0 ? 0 : (q > NB - 1 ? NB - 1 : q);
            atomicAdd(&lh[c * NB + q], ist ? 0x10001u : 1u);
        }
    }
    __syncthreads();

    unsigned int* dst = gh + (size_t)blockIdx.x * HISTW;
    for (int j = threadIdx.x; j < HISTW; j += 256) dst[j] = lh[j];
}

__global__ __launch_bounds__(256) void lovasz_reduce_kernel(
    const unsigned int* __restrict__ gh,
    unsigned int* __restrict__ cnt, unsigned int* __restrict__ tcnt, int nblk)
{
    const int j = blockIdx.x * 256 + threadIdx.x;   // < HISTW (grid sized exactly)
    unsigned int cs = 0, ts = 0;
    for (int b = 0; b < nblk; ++b) {
        const unsigned int w = gh[(size_t)b * HISTW + j];
        cs += w & 0xFFFFu;
        ts += w >> 16;
    }
    cnt[j] = cs;
    tcnt[j] = ts;
}

__global__ __launch_bounds__(512) void lovasz_perclass_kernel(
    const unsigned int* __restrict__ cnt, const unsigned int* __restrict__ tcnt,
    float* __restrict__ pc, int* __restrict__ present)
{
    const int c = blockIdx.x;       // class
    const int d = threadIdx.x;      // 0..511, descending-bin position
    const int bin = (NB - 1) - d;

    __shared__ unsigned int sI[NB];
    __shared__ unsigned int sK[NB];
    __shared__ float acc;

    const unsigned int n = cnt[c * NB + bin];
    const unsigned int m = tcnt[c * NB + bin];
    sI[d] = n;
    sK[d] = m;
    if (d == 0) acc = 0.f;
    __syncthreads();

    // Hillis-Steele inclusive scan over descending-bin order
    for (int off = 1; off < NB; off <<= 1) {
        unsigned int vI = 0, vK = 0;
        if (d >= off) { vI = sI[d - off]; vK = sK[d - off]; }
        __syncthreads();
        sI[d] += vI;
        sK[d] += vK;
        __syncthreads();
    }

    const unsigned int I = sI[d];
    const unsigned int K = sK[d];
    const unsigned int G = sK[NB - 1];   // total target pixels of this class

    float contrib = 0.f;
    if (n > 0u && G > 0u) {
        const float Jc = 1.f - (float)(G - K) / (float)(G + I - K);
        const unsigned int Ip = I - n, Kp = K - m;
        const float Jp = 1.f - (float)(G - Kp) / (float)(G + Ip - Kp); // denom >= G > 0
        const float v = ((float)bin + 0.5f) * (1.f / (float)NB);
        contrib = v * (Jc - Jp);
    }
    atomicAdd(&acc, contrib);
    __syncthreads();
    if (d == 0) {
        pc[c] = acc;
        present[c] = (G > 0u) ? 1 : 0;
    }
}

__global__ void lovasz_final_kernel(const float* __restrict__ pc,
                                    const int* __restrict__ present,
                                    float* __restrict__ out)
{
    if (blockIdx.x == 0 && threadIdx.x == 0) {
        float s = 0.f;
        int np = 0;
        for (int c = 0; c < NCLS; ++c) {
            if (present[c]) { s += pc[c]; ++np; }
        }
        out[0] = s / (float)(np > 0 ? np : 1);
    }
}

extern "C" void kernel_launch(void* const* d_in, const int* in_sizes, int n_in,
                              void* d_out, int out_size, void* d_ws, size_t ws_size,
                              hipStream_t stream)
{
    const float* pred = (const float*)d_in[0];
    const int* tgt    = (const int*)d_in[1];
    float* out        = (float*)d_out;

    unsigned int* ws = (unsigned int*)d_ws;
    // ws layout (u32 units):
    //   [0, 9728)        cnt
    //   [9728, 19456)    tcnt
    //   [19456, 19475)   pc (float)
    //   [19475, 19494)   present (int)
    //   [20480, ...)     per-block histograms (nblk * 9728 u32)
    unsigned int* cnt   = ws;
    unsigned int* tcnt  = ws + HISTW;
    float* pc           = (float*)(ws + 2 * HISTW);
    int* present        = (int*)(ws + 2 * HISTW + NCLS);
    unsigned int* gh    = ws + 20480;

    const size_t reserved = 20480u * 4u;
    const size_t hbytes = (size_t)HISTW * 4u;
    int nblk = 1024;
    const size_t avail = (ws_size > reserved) ? (ws_size - reserved) : 0;
    if ((size_t)nblk * hbytes > avail) nblk = (int)(avail / hbytes);
    if (nblk < 32) nblk = 32;   // keep 16-bit packed block-local counts safe

    hipLaunchKernelGGL(lovasz_hist_kernel, dim3(nblk), dim3(256), 0, stream,
                       pred, tgt, gh);
    hipLaunchKernelGGL(lovasz_reduce_kernel, dim3(HISTW / 256), dim3(256), 0, stream,
                       gh, cnt, tcnt, nblk);
    hipLaunchKernelGGL(lovasz_perclass_kernel, dim3(NCLS), dim3(NB), 0, stream,
                       cnt, tcnt, pc, present);
    hipLaunchKernelGGL(lovasz_final_kernel, dim3(1), dim3(64), 0, stream,
                       pc, present, out);
}

// Round 2
// 61.602 us; speedup vs baseline: 3.2451x; 3.2451x over previous
//
#include <hip/hip_runtime.h>
#include <hip/hip_bf16.h>

// Lovasz-Softmax loss, sort-free histogram formulation.
//
// Math: per class, sorting errors descending and accumulating grad*e is
// invariant to permutation within equal-error runs (jaccard value depends only
// on cumulative (i,k)). Quantizing e in [0,1] into NB linear bins gives exact
// cumulative counts at bin boundaries; using the bin center as representative
// bounds the total error by 1/(2*NB) * (j_N - j_0) <= 1/(2*NB) since the
// jaccard sequence is monotone increasing with j_N = 1. NB=512 -> err <= 1e-3,
// far under the 1.9e-2 harness threshold.
//
// R2 change: the R1 reduce kernel was latency-bound (9728 threads x 1024
// serial strided loads, 1.5% occupancy, 157 us). Now reduced in a (38,32)
// grid to 32 unpacked partials (no atomics), and the final 32-way sum is
// folded into the per-class scan kernel. Hist loads vectorized to float2.

#define NCLS 19
#define NB 512
#define HWSZ 262144          // 512*512
#define NPIX 2097152         // 8*512*512
#define HISTW (NCLS * NB)    // 9728 words per histogram copy
#define RED_SPLIT 32

__global__ __launch_bounds__(256) void lovasz_hist_kernel(
    const float* __restrict__ pred, const int* __restrict__ tgt,
    unsigned int* __restrict__ gh)
{
    __shared__ unsigned int lh[HISTW];   // packed: low16 = count, high16 = target count
    for (int j = threadIdx.x; j < HISTW; j += 256) lh[j] = 0u;
    __syncthreads();

    const int stride = gridDim.x * 256;
    // 2 pixels per iteration (float2 loads, 8B/lane)
    for (int g = blockIdx.x * 256 + threadIdx.x; g < (NPIX >> 1); g += stride) {
        const int idx = g << 1;
        const int b  = idx >> 18;          // / (512*512)
        const int hw = idx & (HWSZ - 1);   // even; float2-aligned
        const float* base = pred + ((size_t)b * NCLS) * HWSZ + hw;

        float x0[NCLS], x1[NCLS];
        #pragma unroll
        for (int c = 0; c < NCLS; ++c) {
            const float2 v = *(const float2*)(base + (size_t)c * HWSZ);
            x0[c] = v.x; x1[c] = v.y;
        }
        const int t0 = tgt[idx];
        const int t1 = tgt[idx + 1];

        float mx0 = x0[0], mx1 = x1[0];
        #pragma unroll
        for (int c = 1; c < NCLS; ++c) { mx0 = fmaxf(mx0, x0[c]); mx1 = fmaxf(mx1, x1[c]); }

        float s0 = 0.f, s1 = 0.f;
        #pragma unroll
        for (int c = 0; c < NCLS; ++c) {
            x0[c] = __expf(x0[c] - mx0); s0 += x0[c];
            x1[c] = __expf(x1[c] - mx1); s1 += x1[c];
        }
        const float inv0 = 1.f / s0, inv1 = 1.f / s1;

        #pragma unroll
        for (int c = 0; c < NCLS; ++c) {
            {
                const float p = x0[c] * inv0;
                const bool ist = (c == t0);
                const float e = ist ? (1.f - p) : p;
                int q = (int)(e * (float)NB);
                q = q < 0 ? 0 : (q > NB - 1 ? NB - 1 : q);
                atomicAdd(&lh[c * NB + q], ist ? 0x10001u : 1u);
            }
            {
                const float p = x1[c] * inv1;
                const bool ist = (c == t1);
                const float e = ist ? (1.f - p) : p;
                int q = (int)(e * (float)NB);
                q = q < 0 ? 0 : (q > NB - 1 ? NB - 1 : q);
                atomicAdd(&lh[c * NB + q], ist ? 0x10001u : 1u);
            }
        }
    }
    __syncthreads();

    unsigned int* dst = gh + (size_t)blockIdx.x * HISTW;
    for (int j = threadIdx.x; j < HISTW; j += 256) dst[j] = lh[j];
}

// Stage A: grid (HISTW/256, RED_SPLIT). Block (jc, k) sums its slice of
// histograms [k*nper, min((k+1)*nper, nblk)) into unpacked partials.
__global__ __launch_bounds__(256) void lovasz_reduce_kernel(
    const unsigned int* __restrict__ gh,
    unsigned int* __restrict__ cntp, unsigned int* __restrict__ tcntp, int nblk)
{
    const int j = blockIdx.x * 256 + threadIdx.x;   // < HISTW (grid sized exactly)
    const int k = blockIdx.y;
    const int nper = (nblk + RED_SPLIT - 1) / RED_SPLIT;
    const int b0 = k * nper;
    int b1 = b0 + nper; if (b1 > nblk) b1 = nblk;

    unsigned int cs = 0, ts = 0;
    for (int b = b0; b < b1; ++b) {
        const unsigned int w = gh[(size_t)b * HISTW + j];
        cs += w & 0xFFFFu;
        ts += w >> 16;
    }
    cntp[(size_t)k * HISTW + j] = cs;
    tcntp[(size_t)k * HISTW + j] = ts;
}

__global__ __launch_bounds__(512) void lovasz_perclass_kernel(
    const unsigned int* __restrict__ cntp, const unsigned int* __restrict__ tcntp,
    float* __restrict__ pc, int* __restrict__ present)
{
    const int c = blockIdx.x;       // class
    const int d = threadIdx.x;      // 0..511, descending-bin position
    const int bin = (NB - 1) - d;
    const int col = c * NB + bin;

    __shared__ unsigned int sI[NB];
    __shared__ unsigned int sK[NB];
    __shared__ float acc;

    unsigned int n = 0, m = 0;
    #pragma unroll
    for (int k = 0; k < RED_SPLIT; ++k) {
        n += cntp[(size_t)k * HISTW + col];
        m += tcntp[(size_t)k * HISTW + col];
    }
    sI[d] = n;
    sK[d] = m;
    if (d == 0) acc = 0.f;
    __syncthreads();

    // Hillis-Steele inclusive scan over descending-bin order
    for (int off = 1; off < NB; off <<= 1) {
        unsigned int vI = 0, vK = 0;
        if (d >= off) { vI = sI[d - off]; vK = sK[d - off]; }
        __syncthreads();
        sI[d] += vI;
        sK[d] += vK;
        __syncthreads();
    }

    const unsigned int I = sI[d];
    const unsigned int K = sK[d];
    const unsigned int G = sK[NB - 1];   // total target pixels of this class

    float contrib = 0.f;
    if (n > 0u && G > 0u) {
        const float Jc = 1.f - (float)(G - K) / (float)(G + I - K);
        const unsigned int Ip = I - n, Kp = K - m;
        const float Jp = 1.f - (float)(G - Kp) / (float)(G + Ip - Kp); // denom >= G > 0
        const float v = ((float)bin + 0.5f) * (1.f / (float)NB);
        contrib = v * (Jc - Jp);
    }
    atomicAdd(&acc, contrib);
    __syncthreads();
    if (d == 0) {
        pc[c] = acc;
        present[c] = (G > 0u) ? 1 : 0;
    }
}

__global__ void lovasz_final_kernel(const float* __restrict__ pc,
                                    const int* __restrict__ present,
                                    float* __restrict__ out)
{
    if (blockIdx.x == 0 && threadIdx.x == 0) {
        float s = 0.f;
        int np = 0;
        for (int c = 0; c < NCLS; ++c) {
            if (present[c]) { s += pc[c]; ++np; }
        }
        out[0] = s / (float)(np > 0 ? np : 1);
    }
}

extern "C" void kernel_launch(void* const* d_in, const int* in_sizes, int n_in,
                              void* d_out, int out_size, void* d_ws, size_t ws_size,
                              hipStream_t stream)
{
    const float* pred = (const float*)d_in[0];
    const int* tgt    = (const int*)d_in[1];
    float* out        = (float*)d_out;

    unsigned int* ws = (unsigned int*)d_ws;
    // ws layout (u32 word offsets):
    //   [0, 311296)         cntp   (RED_SPLIT * HISTW)
    //   [311296, 622592)    tcntp  (RED_SPLIT * HISTW)
    //   [622592, 622611)    pc (float)
    //   [622611, 622630)    present (int)
    //   [655360, ...)       per-block histograms (nblk * HISTW u32)
    unsigned int* cntp  = ws;
    unsigned int* tcntp = ws + RED_SPLIT * HISTW;
    float* pc           = (float*)(ws + 2 * RED_SPLIT * HISTW);
    int* present        = (int*)(ws + 2 * RED_SPLIT * HISTW + NCLS);
    unsigned int* gh    = ws + 655360;

    const size_t reserved = 655360u * 4u;
    const size_t hbytes = (size_t)HISTW * 4u;
    int nblk = 1024;
    const size_t avail = (ws_size > reserved) ? (ws_size - reserved) : 0;
    if ((size_t)nblk * hbytes > avail) nblk = (int)(avail / hbytes);
    if (nblk < 32) nblk = 32;   // keep 16-bit packed block-local counts safe

    hipLaunchKernelGGL(lovasz_hist_kernel, dim3(nblk), dim3(256), 0, stream,
                       pred, tgt, gh);
    hipLaunchKernelGGL(lovasz_reduce_kernel, dim3(HISTW / 256, RED_SPLIT), dim3(256), 0, stream,
                       gh, cntp, tcntp, nblk);
    hipLaunchKernelGGL(lovasz_perclass_kernel, dim3(NCLS), dim3(NB), 0, stream,
                       cntp, tcntp, pc, present);
    hipLaunchKernelGGL(lovasz_final_kernel, dim3(1), dim3(64), 0, stream,
                       pc, present, out);
}

// Round 3
// 59.501 us; speedup vs baseline: 3.3597x; 1.0353x over previous
//
#include <hip/hip_runtime.h>
#include <hip/hip_bf16.h>

// Lovasz-Softmax loss, sort-free histogram formulation.
//
// Math: per class, sorting errors descending and accumulating grad*e is
// invariant to permutation within equal-error runs (jaccard value depends only
// on cumulative (i,k)). Quantizing e in [0,1] into NB linear bins gives exact
// cumulative counts at bin boundaries; using the bin center as representative
// bounds the total error by 1/(2*NB) <= 1e-3, far under the 1.9e-2 threshold.
//
// R3: nblk 1024->512 (halves histogram scratch round-trip 80->40 MB total),
// float4 loads (4 pixels/thread/iter). Compulsory traffic 327 MB read -> ~50us
// floor at the ~7 TB/s observed streaming rate.

#define NCLS 19
#define NB 512
#define HWSZ 262144          // 512*512
#define NPIX 2097152         // 8*512*512
#define HISTW (NCLS * NB)    // 9728 words per histogram copy
#define RED_SPLIT 32
#define NBLK 512

__global__ __launch_bounds__(256) void lovasz_hist_kernel(
    const float* __restrict__ pred, const int* __restrict__ tgt,
    unsigned int* __restrict__ gh)
{
    __shared__ unsigned int lh[HISTW];   // packed: low16 = count, high16 = target count
    for (int j = threadIdx.x; j < HISTW; j += 256) lh[j] = 0u;
    __syncthreads();

    const int stride = gridDim.x * 256;
    // 4 pixels per iteration (float4 / int4 loads)
    for (int g = blockIdx.x * 256 + threadIdx.x; g < (NPIX >> 2); g += stride) {
        const int idx = g << 2;
        const int b  = idx >> 18;          // / (512*512)
        const int hw = idx & (HWSZ - 1);   // multiple of 4; 16B-aligned
        const float* base = pred + ((size_t)b * NCLS) * HWSZ + hw;

        float x0[NCLS], x1[NCLS], x2[NCLS], x3[NCLS];
        #pragma unroll
        for (int c = 0; c < NCLS; ++c) {
            const float4 v = *(const float4*)(base + (size_t)c * HWSZ);
            x0[c] = v.x; x1[c] = v.y; x2[c] = v.z; x3[c] = v.w;
        }
        const int4 t4 = *(const int4*)(tgt + idx);

        float mx0 = x0[0], mx1 = x1[0], mx2 = x2[0], mx3 = x3[0];
        #pragma unroll
        for (int c = 1; c < NCLS; ++c) {
            mx0 = fmaxf(mx0, x0[c]); mx1 = fmaxf(mx1, x1[c]);
            mx2 = fmaxf(mx2, x2[c]); mx3 = fmaxf(mx3, x3[c]);
        }

        float s0 = 0.f, s1 = 0.f, s2 = 0.f, s3 = 0.f;
        #pragma unroll
        for (int c = 0; c < NCLS; ++c) {
            x0[c] = __expf(x0[c] - mx0); s0 += x0[c];
            x1[c] = __expf(x1[c] - mx1); s1 += x1[c];
            x2[c] = __expf(x2[c] - mx2); s2 += x2[c];
            x3[c] = __expf(x3[c] - mx3); s3 += x3[c];
        }
        const float inv0 = 1.f / s0, inv1 = 1.f / s1;
        const float inv2 = 1.f / s2, inv3 = 1.f / s3;

        #pragma unroll
        for (int c = 0; c < NCLS; ++c) {
            {
                const float p = x0[c] * inv0;
                const bool ist = (c == t4.x);
                const float e = ist ? (1.f - p) : p;
                int q = (int)(e * (float)NB);
                q = q < 0 ? 0 : (q > NB - 1 ? NB - 1 : q);
                atomicAdd(&lh[c * NB + q], ist ? 0x10001u : 1u);
            }
            {
                const float p = x1[c] * inv1;
                const bool ist = (c == t4.y);
                const float e = ist ? (1.f - p) : p;
                int q = (int)(e * (float)NB);
                q = q < 0 ? 0 : (q > NB - 1 ? NB - 1 : q);
                atomicAdd(&lh[c * NB + q], ist ? 0x10001u : 1u);
            }
            {
                const float p = x2[c] * inv2;
                const bool ist = (c == t4.z);
                const float e = ist ? (1.f - p) : p;
                int q = (int)(e * (float)NB);
                q = q < 0 ? 0 : (q > NB - 1 ? NB - 1 : q);
                atomicAdd(&lh[c * NB + q], ist ? 0x10001u : 1u);
            }
            {
                const float p = x3[c] * inv3;
                const bool ist = (c == t4.w);
                const float e = ist ? (1.f - p) : p;
                int q = (int)(e * (float)NB);
                q = q < 0 ? 0 : (q > NB - 1 ? NB - 1 : q);
                atomicAdd(&lh[c * NB + q], ist ? 0x10001u : 1u);
            }
        }
    }
    __syncthreads();

    unsigned int* dst = gh + (size_t)blockIdx.x * HISTW;
    for (int j = threadIdx.x; j < HISTW; j += 256) dst[j] = lh[j];
}

// Stage A: grid (HISTW/256, RED_SPLIT). Block (jc, k) sums histograms
// [k*nper, (k+1)*nper) into unpacked partials.
__global__ __launch_bounds__(256) void lovasz_reduce_kernel(
    const unsigned int* __restrict__ gh,
    unsigned int* __restrict__ cntp, unsigned int* __restrict__ tcntp, int nblk)
{
    const int j = blockIdx.x * 256 + threadIdx.x;   // < HISTW (grid sized exactly)
    const int k = blockIdx.y;
    const int nper = (nblk + RED_SPLIT - 1) / RED_SPLIT;
    const int b0 = k * nper;
    int b1 = b0 + nper; if (b1 > nblk) b1 = nblk;

    unsigned int cs = 0, ts = 0;
    for (int b = b0; b < b1; ++b) {
        const unsigned int w = gh[(size_t)b * HISTW + j];
        cs += w & 0xFFFFu;
        ts += w >> 16;
    }
    cntp[(size_t)k * HISTW + j] = cs;
    tcntp[(size_t)k * HISTW + j] = ts;
}

__global__ __launch_bounds__(512) void lovasz_perclass_kernel(
    const unsigned int* __restrict__ cntp, const unsigned int* __restrict__ tcntp,
    float* __restrict__ pc, int* __restrict__ present)
{
    const int c = blockIdx.x;       // class
    const int d = threadIdx.x;      // 0..511, descending-bin position
    const int bin = (NB - 1) - d;
    const int col = c * NB + bin;

    __shared__ unsigned int sI[NB];
    __shared__ unsigned int sK[NB];
    __shared__ float acc;

    unsigned int n = 0, m = 0;
    #pragma unroll
    for (int k = 0; k < RED_SPLIT; ++k) {
        n += cntp[(size_t)k * HISTW + col];
        m += tcntp[(size_t)k * HISTW + col];
    }
    sI[d] = n;
    sK[d] = m;
    if (d == 0) acc = 0.f;
    __syncthreads();

    // Hillis-Steele inclusive scan over descending-bin order
    for (int off = 1; off < NB; off <<= 1) {
        unsigned int vI = 0, vK = 0;
        if (d >= off) { vI = sI[d - off]; vK = sK[d - off]; }
        __syncthreads();
        sI[d] += vI;
        sK[d] += vK;
        __syncthreads();
    }

    const unsigned int I = sI[d];
    const unsigned int K = sK[d];
    const unsigned int G = sK[NB - 1];   // total target pixels of this class

    float contrib = 0.f;
    if (n > 0u && G > 0u) {
        const float Jc = 1.f - (float)(G - K) / (float)(G + I - K);
        const unsigned int Ip = I - n, Kp = K - m;
        const float Jp = 1.f - (float)(G - Kp) / (float)(G + Ip - Kp); // denom >= G > 0
        const float v = ((float)bin + 0.5f) * (1.f / (float)NB);
        contrib = v * (Jc - Jp);
    }
    atomicAdd(&acc, contrib);
    __syncthreads();
    if (d == 0) {
        pc[c] = acc;
        present[c] = (G > 0u) ? 1 : 0;
    }
}

__global__ void lovasz_final_kernel(const float* __restrict__ pc,
                                    const int* __restrict__ present,
                                    float* __restrict__ out)
{
    if (blockIdx.x == 0 && threadIdx.x == 0) {
        float s = 0.f;
        int np = 0;
        for (int c = 0; c < NCLS; ++c) {
            if (present[c]) { s += pc[c]; ++np; }
        }
        out[0] = s / (float)(np > 0 ? np : 1);
    }
}

extern "C" void kernel_launch(void* const* d_in, const int* in_sizes, int n_in,
                              void* d_out, int out_size, void* d_ws, size_t ws_size,
                              hipStream_t stream)
{
    const float* pred = (const float*)d_in[0];
    const int* tgt    = (const int*)d_in[1];
    float* out        = (float*)d_out;

    unsigned int* ws = (unsigned int*)d_ws;
    // ws layout (u32 word offsets):
    //   [0, 311296)         cntp   (RED_SPLIT * HISTW)
    //   [311296, 622592)    tcntp  (RED_SPLIT * HISTW)
    //   [622592, 622611)    pc (float)
    //   [622611, 622630)    present (int)
    //   [655360, ...)       per-block histograms (nblk * HISTW u32)
    unsigned int* cntp  = ws;
    unsigned int* tcntp = ws + RED_SPLIT * HISTW;
    float* pc           = (float*)(ws + 2 * RED_SPLIT * HISTW);
    int* present        = (int*)(ws + 2 * RED_SPLIT * HISTW + NCLS);
    unsigned int* gh    = ws + 655360;

    const size_t reserved = 655360u * 4u;
    const size_t hbytes = (size_t)HISTW * 4u;
    int nblk = NBLK;
    const size_t avail = (ws_size > reserved) ? (ws_size - reserved) : 0;
    if ((size_t)nblk * hbytes > avail) nblk = (int)(avail / hbytes);
    if (nblk < 32) nblk = 32;   // keep 16-bit packed block-local counts safe

    hipLaunchKernelGGL(lovasz_hist_kernel, dim3(nblk), dim3(256), 0, stream,
                       pred, tgt, gh);
    hipLaunchKernelGGL(lovasz_reduce_kernel, dim3(HISTW / 256, RED_SPLIT), dim3(256), 0, stream,
                       gh, cntp, tcntp, nblk);
    hipLaunchKernelGGL(lovasz_perclass_kernel, dim3(NCLS), dim3(NB), 0, stream,
                       cntp, tcntp, pc, present);
    hipLaunchKernelGGL(lovasz_final_kernel, dim3(1), dim3(64), 0, stream,
                       pc, present, out);
}